// Round 2
// baseline (294.505 us; speedup 1.0000x reference)
//
#include <hip/hip_runtime.h>
#include <hip/hip_bf16.h>
#include <stdint.h>

typedef __attribute__((ext_vector_type(8))) short short8;
typedef __attribute__((ext_vector_type(4))) float f32x4;

#define NBATCH 4096
#define NNODE  17
#define NDIM   512
#define ROWLEN 8704   // 17*512

__device__ __forceinline__ unsigned short f2bf(float f) {
    union { float f; unsigned int u; } v; v.f = f;
    unsigned int r = v.u + 0x7fffu + ((v.u >> 16) & 1u);   // round-nearest-even
    return (unsigned short)(r >> 16);
}
__device__ __forceinline__ unsigned int pk2(unsigned short a, unsigned short b) {
    return (unsigned int)a | ((unsigned int)b << 16);
}
__device__ __forceinline__ float silu_f(float x) {
    return x / (1.0f + __expf(-x));
}

// ---------------------------------------------------------------------------
// Kernel 1: bid 0        : L = I - D^-1/2 A D^-1/2  -> Lw[289]
//           bid [1,129)  : transpose-cast W_mod [512][1024] f32 -> wbT [1024][512] bf16
//           bid [129,1153): cb[b][c] = bf16(silu(c_in[b][c]))
// ---------------------------------------------------------------------------
__global__ __launch_bounds__(256) void prep_kernel(
        const float* __restrict__ cin, const float* __restrict__ Wmod,
        const float* __restrict__ adj,
        unsigned short* __restrict__ cb, unsigned short* __restrict__ wbT,
        float* __restrict__ Lw) {
    int bid = blockIdx.x;
    int tid = threadIdx.x;
    if (bid == 0) {
        __shared__ float dsh[17];
        if (tid < 17) {
            float rs = 0.0f;
            #pragma unroll
            for (int j = 0; j < 17; ++j) rs += adj[tid * 17 + j];
            dsh[tid] = rsqrtf(rs);
        }
        __syncthreads();
        for (int e = tid; e < 289; e += 256) {
            int i = e / 17, j = e - i * 17;
            Lw[e] = (i == j ? 1.0f : 0.0f) - dsh[i] * adj[e] * dsh[j];
        }
    } else if (bid < 129) {
        __shared__ float tile[64][65];
        int bt = bid - 1;
        int txt = bt & 15, tyt = bt >> 4;        // col-tile (1024/64), row-tile (512/64)
        int cx = tid & 63, ry = tid >> 6;
        #pragma unroll
        for (int rr = 0; rr < 16; ++rr) {
            int r = ry + rr * 4;
            tile[r][cx] = Wmod[(tyt*64 + r) * 1024 + txt*64 + cx];
        }
        __syncthreads();
        #pragma unroll
        for (int rr = 0; rr < 16; ++rr) {
            int r = ry + rr * 4;
            wbT[(txt*64 + r) * 512 + tyt*64 + cx] = f2bf(tile[cx][r]);
        }
    } else {
        int t = (bid - 129) * 256 + tid;          // < 262144, 8 elems each
        const float4* s = reinterpret_cast<const float4*>(cin) + (size_t)t * 2;
        float4 a = s[0], b = s[1];
        uint4 o;
        o.x = pk2(f2bf(silu_f(a.x)), f2bf(silu_f(a.y)));
        o.y = pk2(f2bf(silu_f(a.z)), f2bf(silu_f(a.w)));
        o.z = pk2(f2bf(silu_f(b.x)), f2bf(silu_f(b.y)));
        o.w = pk2(f2bf(silu_f(b.z)), f2bf(silu_f(b.w)));
        *reinterpret_cast<uint4*>(cb + (size_t)t * 8) = o;
    }
}

// ---------------------------------------------------------------------------
// Kernel 2: H[4096][1024] = cb[4096][512] @ wbT^T + b_mod   (MFMA bf16)
// ---------------------------------------------------------------------------
__global__ __launch_bounds__(256) void gemm_kernel(
        const unsigned short* __restrict__ cb, const unsigned short* __restrict__ wbT,
        const float* __restrict__ b_mod, float* __restrict__ H) {
    int w = threadIdx.x >> 6, l = threadIdx.x & 63;
    int lr = l & 15, lk = (l >> 4) * 8;
    int rowbase = blockIdx.y * 128 + w * 32;
    int colbase = blockIdx.x * 64;
    f32x4 acc[2][4] = {};
    for (int kk = 0; kk < 16; ++kk) {
        int k = kk * 32 + lk;
        short8 a0 = *reinterpret_cast<const short8*>(cb + (size_t)(rowbase + lr) * 512 + k);
        short8 a1 = *reinterpret_cast<const short8*>(cb + (size_t)(rowbase + 16 + lr) * 512 + k);
        #pragma unroll
        for (int j = 0; j < 4; ++j) {
            short8 bv = *reinterpret_cast<const short8*>(wbT + (size_t)(colbase + j*16 + lr) * 512 + k);
            acc[0][j] = __builtin_amdgcn_mfma_f32_16x16x32_bf16(a0, bv, acc[0][j], 0, 0, 0);
            acc[1][j] = __builtin_amdgcn_mfma_f32_16x16x32_bf16(a1, bv, acc[1][j], 0, 0, 0);
        }
    }
    #pragma unroll
    for (int j = 0; j < 4; ++j) {
        int col = colbase + j * 16 + lr;
        float bm = b_mod[col];
        #pragma unroll
        for (int i = 0; i < 2; ++i) {
            int row0 = rowbase + i * 16 + (l >> 4) * 4;
            #pragma unroll
            for (int r = 0; r < 4; ++r)
                H[(size_t)(row0 + r) * 1024 + col] = acc[i][j][r] + bm;
        }
    }
}

// ---------------------------------------------------------------------------
// Kernel 3: fused LayerNorm + modulate + Cheb projection + graph combine.
// 2 batches per block, 512 threads (8 waves). All-f32 P path (no MFMA):
// 36 tasks (2 slots x 18 rows; row 17 = shift row). Each wave owns 4-5 tasks:
//   per task: 64-lane LN reduce -> xs = xn*(1+scale) (or shift) ->
//   p[r] = sum_j xs_j * Wt[r][8l+j] -> 64-lane butterfly -> P_s row.
// Then out = (P0+S0) - (P2+S2) + L@(P1+S1 + 2*(L@(P2+S2))) + bg.
// ---------------------------------------------------------------------------
__global__ __launch_bounds__(512, 4) void main_kernel(
        const float* __restrict__ x, const float* __restrict__ Lw,
        const float* __restrict__ Wg, const float* __restrict__ bg,
        const float* __restrict__ H, float* __restrict__ out) {
    __shared__ float Wt[9][520];        // Wt[k*3+o][c] = Wg[k][c][o]
    __shared__ float L_s[17][20];
    __shared__ float P_s[2][18][12];    // cols 0-8: P rows (row 17 = S); cols 9-11: Q

    int tid = threadIdx.x;
    int w = tid >> 6, l = tid & 63;
    int b0 = blockIdx.x * 2;

    // ---- Phase A: prefetch x / shift rows for this wave's tasks + scale vecs ----
    float xv[5][8];
    int tslot[5], tnode[5];
    #pragma unroll
    for (int i = 0; i < 5; ++i) {
        int t = w + i * 8;
        int tc = t < 36 ? t : 35;
        int slot = tc >= 18 ? 1 : 0;
        int node = tc - slot * 18;
        tslot[i] = slot; tnode[i] = node;
        const float* src = (node < 17)
            ? x + (size_t)(b0 + slot) * ROWLEN + node * 512 + 8 * l
            : H + (size_t)(b0 + slot) * 1024 + 8 * l;      // shift row
        float4 a = reinterpret_cast<const float4*>(src)[0];
        float4 c4 = reinterpret_cast<const float4*>(src)[1];
        xv[i][0]=a.x;  xv[i][1]=a.y;  xv[i][2]=a.z;  xv[i][3]=a.w;
        xv[i][4]=c4.x; xv[i][5]=c4.y; xv[i][6]=c4.z; xv[i][7]=c4.w;
    }
    float fs0[8], fs1[8];
    {
        const float4* h0 = reinterpret_cast<const float4*>(H + (size_t)b0 * 1024 + 512 + 8 * l);
        const float4* h1 = reinterpret_cast<const float4*>(H + (size_t)(b0 + 1) * 1024 + 512 + 8 * l);
        float4 a = h0[0], b = h0[1], c4 = h1[0], d4 = h1[1];
        fs0[0]=1.f+a.x; fs0[1]=1.f+a.y; fs0[2]=1.f+a.z; fs0[3]=1.f+a.w;
        fs0[4]=1.f+b.x; fs0[5]=1.f+b.y; fs0[6]=1.f+b.z; fs0[7]=1.f+b.w;
        fs1[0]=1.f+c4.x; fs1[1]=1.f+c4.y; fs1[2]=1.f+c4.z; fs1[3]=1.f+c4.w;
        fs1[4]=1.f+d4.x; fs1[5]=1.f+d4.y; fs1[6]=1.f+d4.z; fs1[7]=1.f+d4.w;
    }

    // ---- LDS fills: Wg transpose (all 512 threads) + L ----
    {
        int c = tid;
        #pragma unroll
        for (int k = 0; k < 3; ++k) {
            float w0 = Wg[k * 1536 + c * 3 + 0];
            float w1 = Wg[k * 1536 + c * 3 + 1];
            float w2 = Wg[k * 1536 + c * 3 + 2];
            Wt[k * 3 + 0][c] = w0;
            Wt[k * 3 + 1][c] = w1;
            Wt[k * 3 + 2][c] = w2;
        }
    }
    if (tid < 289) {
        int i2 = tid / 17, j2 = tid - i2 * 17;
        L_s[i2][j2] = Lw[tid];
    }
    __syncthreads();

    // ---- Phase B: per-task LN + projection + wave reduce ----
    #pragma unroll
    for (int i = 0; i < 5; ++i) {
        int t = w + i * 8;
        if (t < 36) {
            float xs[8];
            if (tnode[i] < 17) {
                float s = 0.0f, s2 = 0.0f;
                #pragma unroll
                for (int j = 0; j < 8; ++j) { s += xv[i][j]; s2 += xv[i][j] * xv[i][j]; }
                #pragma unroll
                for (int m = 1; m < 64; m <<= 1) { s += __shfl_xor(s, m); s2 += __shfl_xor(s2, m); }
                float mu = s * (1.0f / 512.0f);
                float var = s2 * (1.0f / 512.0f) - mu * mu;
                float rstd = rsqrtf(var + 1e-6f);
                #pragma unroll
                for (int j = 0; j < 8; ++j) {
                    float fj = tslot[i] ? fs1[j] : fs0[j];
                    xs[j] = (xv[i][j] - mu) * rstd * fj;
                }
            } else {
                #pragma unroll
                for (int j = 0; j < 8; ++j) xs[j] = xv[i][j];
            }
            float p[9];
            #pragma unroll
            for (int r = 0; r < 9; ++r) {
                float4 w0 = *reinterpret_cast<const float4*>(&Wt[r][8 * l]);
                float4 w1 = *reinterpret_cast<const float4*>(&Wt[r][8 * l + 4]);
                p[r] = xs[0]*w0.x + xs[1]*w0.y + xs[2]*w0.z + xs[3]*w0.w
                     + xs[4]*w1.x + xs[5]*w1.y + xs[6]*w1.z + xs[7]*w1.w;
            }
            #pragma unroll
            for (int m = 1; m < 64; m <<= 1) {
                #pragma unroll
                for (int r = 0; r < 9; ++r) p[r] += __shfl_xor(p[r], m);
            }
            if (l == 0) {
                #pragma unroll
                for (int r = 0; r < 9; ++r) P_s[tslot[i]][tnode[i]][r] = p[r];
            }
        }
    }
    __syncthreads();

    // ---- Phase C1: Q = L @ (P2 + S2)  ->  P_s[slot][n][9+o] ----
    if (tid < 102) {
        int slot = tid / 51, q = tid - slot * 51;
        int n = q / 3, o = q - n * 3;
        float s2v = P_s[slot][17][6 + o];
        float acc = 0.0f;
        #pragma unroll
        for (int m = 0; m < 17; ++m) acc += L_s[n][m] * (P_s[slot][m][6 + o] + s2v);
        P_s[slot][n][9 + o] = acc;
    }
    __syncthreads();

    // ---- Phase C2: out = (P0+S0) - (P2+S2) + L@(P1+S1 + 2Q) + bg ----
    if (tid < 102) {
        int slot = tid / 51, q = tid - slot * 51;
        int n = q / 3, o = q - n * 3;
        float s0v = P_s[slot][17][o];
        float s1v = P_s[slot][17][3 + o];
        float s2v = P_s[slot][17][6 + o];
        float r = P_s[slot][n][o] + s0v - P_s[slot][n][6 + o] - s2v + bg[o];
        #pragma unroll
        for (int m = 0; m < 17; ++m)
            r += L_s[n][m] * (P_s[slot][m][3 + o] + s1v + 2.0f * P_s[slot][m][9 + o]);
        out[(size_t)(b0 + slot) * 51 + q] = r;
    }
}

// ---------------------------------------------------------------------------
extern "C" void kernel_launch(void* const* d_in, const int* in_sizes, int n_in,
                              void* d_out, int out_size, void* d_ws, size_t ws_size,
                              hipStream_t stream) {
    const float* x     = (const float*)d_in[0];
    const float* adj   = (const float*)d_in[1];
    const float* c     = (const float*)d_in[2];
    const float* W_mod = (const float*)d_in[3];
    const float* b_mod = (const float*)d_in[4];
    const float* Wg    = (const float*)d_in[5];
    const float* bg    = (const float*)d_in[6];
    float* out = (float*)d_out;

    // workspace: cb 4MB @0 | wbT 1MB @4MB | H 16MB @5MB | Lw @21MB
    unsigned short* cb  = (unsigned short*)d_ws;
    unsigned short* wbT = (unsigned short*)((char*)d_ws + (4u << 20));
    float*          H   = (float*)((char*)d_ws + (5u << 20));
    float*          Lw  = (float*)((char*)d_ws + (21u << 20));

    prep_kernel<<<1153, 256, 0, stream>>>(c, W_mod, adj, cb, wbT, Lw);
    gemm_kernel<<<dim3(16, 32), 256, 0, stream>>>(cb, wbT, b_mod, H);
    main_kernel<<<2048, 512, 0, stream>>>(x, Lw, Wg, bg, H, out);
}